// Round 5
// baseline (177.897 us; speedup 1.0000x reference)
//
#include <hip/hip_runtime.h>

#define EPS 1e-6f

// C2 = FIXED_T/(NUM_LEVELS-1) * log2(e) = 100/(15*ln2);  g = 2^-C2 = exp(-100/15)
static constexpr float C2  = 9.617966939259756f;
static constexpr float GK  = 1.2726338013398079e-3f;  // g
static constexpr float C1  = 1.0012742546176476f;     // 1/(1-g)
static constexpr float C2P = 1.0025501329047173f;     // 1/(1-g)^2
static constexpr float C3  = 0.9987273661986602f;     // 1-g
static constexpr float C4  = 14.982183126781242f;     // 15 - 14g

typedef float floatx4 __attribute__((ext_vector_type(4)));

#if __has_builtin(__builtin_amdgcn_exp2f)
__device__ __forceinline__ float fast_exp2(float x) { return __builtin_amdgcn_exp2f(x); }
#else
__device__ __forceinline__ float fast_exp2(float x) { return exp2f(x); }
#endif

#if __has_builtin(__builtin_amdgcn_rcpf)
__device__ __forceinline__ float fast_rcp(float x) { return __builtin_amdgcn_rcpf(x); }
#else
__device__ __forceinline__ float fast_rcp(float x) { return 1.0f / x; }
#endif

// deterministic block-wide sum for 512 threads (8 waves); red has 8 floats/slot
__device__ __forceinline__ float block_sum_512(float v, float* red, int slot) {
    #pragma unroll
    for (int o = 32; o > 0; o >>= 1) v += __shfl_xor(v, o, 64);
    const int t = threadIdx.x;
    __syncthreads();  // protect prior use of red
    if ((t & 63) == 0) red[slot * 8 + (t >> 6)] = v;
    __syncthreads();
    float s = 0.0f;
    #pragma unroll
    for (int wv = 0; wv < 8; ++wv) s += red[slot * 8 + wv];
    return s;
}

__global__ __launch_bounds__(512) void bq_main_kernel(
    const float* __restrict__ weight,
    const float* __restrict__ w_min,
    const float* __restrict__ w_max,
    float* __restrict__ out,
    float* __restrict__ ent_partial)
{
    // U[n][slot] then V[n][slot]; slot = cq + 32k (bank = cq -> 2-way, free)
    __shared__ float UV[2 * 16 * 128];   // 16 KB
    __shared__ float red[16];

    const int bid = blockIdx.x;
    const int br = bid >> 5;
    const int bc = bid & 31;
    const int t = threadIdx.x;      // 0..511
    const int cq = t & 31;          // column quad (cols 4cq..4cq+3)
    const int rg = t >> 5;          // row group (16 groups x 8 rows)

    #pragma unroll
    for (int i = 0; i < 8; ++i) UV[t + i * 512] = 0.0f;

    // per-block scale params (reference semantics)
    const float wmn = w_min[bid];
    const float wmx = w_max[bid];
    const float lo = fminf(wmn, wmx - EPS);
    const float hi = fmaxf(wmx, lo + EPS);
    const float scale = hi - lo + EPS;
    const float s15 = 15.0f / scale;
    const float dmm15 = (hi - lo) * (1.0f / 15.0f);
    const float tb0 = -lo * s15;    // th = fmaf(w, s15, tb0)

    __syncthreads();

    const size_t base = (size_t)(br * 128 + rg * 8) * 4096 + (size_t)(bc * 128 + cq * 4);
    const floatx4* __restrict__ wp = (const floatx4*)(weight + base);
    floatx4* __restrict__ op = (floatx4*)(out + base);

    float* U = UV;
    float* V = UV + 2048;

    #pragma unroll 2
    for (int i = 0; i < 8; ++i) {
        const floatx4 w4 = wp[(size_t)i * 1024];
        floatx4 o4;
        #pragma unroll
        for (int k = 0; k < 4; ++k) {
            const float th = fmaf(w4[k], s15, tb0);         // 15*w_norm in [0,15)
            const float nf = fminf(fmaxf(floorf(th), 0.0f), 15.0f);
            const int n = (int)nf;
            const float f = th - nf;                        // [0,1)
            // geometric closed form: S = C1*(q + r - s - t2)
            const float q  = fast_exp2(-C2 * f);            // g^f
            const float r  = fast_exp2(fmaf(C2, f, -C2));   // g^(1-f)
            const float s  = fast_exp2(fmaf(-C2, th, -C2)); // g^(th+1)
            const float t2 = fast_exp2(fmaf(C2, th, -16.0f * C2)); // g^(16-th)
            const float x  = fmaf(C2, th, -7.5f * C2);
            const float P  = fast_exp2(x);                  // g^(7.5-th)
            const float Pi = fast_exp2(-x);                 // g^(th-7.5)
            const float S  = C1 * ((q + r) - (s + t2));
            const float rS = fast_rcp(S);
            // 15W = n*S + (r-t2)*C1 + [g(r-q) + s*A - t2*B]*C2P
            const float A  = fmaf(nf, C3, 1.0f);            // (n+1) - n*g
            const float B  = fmaf(-nf, C3, C4);             // (15-n) - (14-n)*g
            const float T2 = fmaf(s, A, fmaf(-t2, B, (r - q) * GK));
            const float W15 = fmaf(nf, S, fmaf(r - t2, C1, T2 * C2P));
            o4[k] = fmaf(W15 * rS, dmm15, lo);
            const int slot = n * 128 + cq + (k << 5);
            atomicAdd(&U[slot], Pi * rS);                   // ds_add_f32, no chain
            atomicAdd(&V[slot], P * rS);
        }
        __builtin_nontemporal_store(o4, &op[(size_t)i * 1024]);
    }

    __syncthreads();

    // epilogue: bins per column-slot from U/V via suffix/prefix, then entropy
    float s_local = 0.0f, ent = 0.0f;
    float bin[16];
    if (t < 128) {
        float suf = 0.0f;
        #pragma unroll
        for (int j = 15; j >= 0; --j) {
            suf += U[j * 128 + t];
            bin[j] = suf * fast_exp2(C2 * ((float)j - 7.5f));       // K[15-j]*SufU
        }
        float pre = 0.0f;
        #pragma unroll
        for (int j = 0; j < 16; ++j) {
            bin[j] = fmaf(pre, fast_exp2(C2 * (7.5f - (float)j)), bin[j]);  // +K[j]*PreV
            pre += V[j * 128 + t];
            s_local += bin[j];
        }
    }

    const float B = block_sum_512(s_local, red, 0);
    const float invB = fast_rcp(B + EPS);

    if (t < 128) {
        #pragma unroll
        for (int j = 0; j < 16; ++j) {
            const float p = bin[j] * invB;
            ent = fmaf(p, __logf(p + EPS), ent);
        }
    }
    const float entB = block_sum_512(ent, red, 1);
    if (t == 0) ent_partial[bid] = -entB;
}

__global__ __launch_bounds__(256) void bq_ent_reduce(
    const float* __restrict__ part, float* __restrict__ out_ent)
{
    __shared__ float red[8];
    const int t = threadIdx.x;  // 256 threads, 1024 partials
    float v = part[t] + part[t + 256] + part[t + 512] + part[t + 768];
    #pragma unroll
    for (int o = 32; o > 0; o >>= 1) v += __shfl_xor(v, o, 64);
    if ((t & 63) == 0) red[t >> 6] = v;
    __syncthreads();
    if (t == 0) out_ent[0] = red[0] + red[1] + red[2] + red[3];
}

extern "C" void kernel_launch(void* const* d_in, const int* in_sizes, int n_in,
                              void* d_out, int out_size, void* d_ws, size_t ws_size,
                              hipStream_t stream) {
    const float* weight = (const float*)d_in[0];
    const float* wmin = (const float*)d_in[1];
    const float* wmax = (const float*)d_in[2];
    float* out = (float*)d_out;
    float* part = (float*)d_ws;  // 1024 floats of scratch

    bq_main_kernel<<<1024, 512, 0, stream>>>(weight, wmin, wmax, out, part);
    bq_ent_reduce<<<1, 256, 0, stream>>>(part, out + (out_size - 1));
}

// Round 6
// 38.170 us; speedup vs baseline: 4.6607x; 4.6607x over previous
//
#include <hip/hip_runtime.h>

#define EPS 1e-6f

// C2 = FIXED_T/(NUM_LEVELS-1) * log2(e) = 100/(15*ln2);  g = 2^-C2 = exp(-100/15)
static constexpr float C2  = 9.617966939259756f;
static constexpr float GK  = 1.2726338013398079e-3f;  // g
static constexpr float C1  = 1.0012742546176476f;     // 1/(1-g)
static constexpr float C2P = 1.0025501329047173f;     // 1/(1-g)^2
static constexpr float C3  = 0.9987273661986602f;     // 1-g
static constexpr float C4  = 14.982183126781242f;     // 15 - 14g

#if __has_builtin(__builtin_amdgcn_exp2f)
__device__ __forceinline__ float fast_exp2(float x) { return __builtin_amdgcn_exp2f(x); }
#else
__device__ __forceinline__ float fast_exp2(float x) { return exp2f(x); }
#endif

#if __has_builtin(__builtin_amdgcn_rcpf)
__device__ __forceinline__ float fast_rcp(float x) { return __builtin_amdgcn_rcpf(x); }
#else
__device__ __forceinline__ float fast_rcp(float x) { return 1.0f / x; }
#endif

// deterministic block-wide sum for 512 threads (8 waves); red has 8 floats/slot
__device__ __forceinline__ float block_sum_512(float v, float* red, int slot) {
    #pragma unroll
    for (int o = 32; o > 0; o >>= 1) v += __shfl_xor(v, o, 64);
    const int t = threadIdx.x;
    __syncthreads();  // protect prior use of red
    if ((t & 63) == 0) red[slot * 8 + (t >> 6)] = v;
    __syncthreads();
    float s = 0.0f;
    #pragma unroll
    for (int wv = 0; wv < 8; ++wv) s += red[slot * 8 + wv];
    return s;
}

__global__ __launch_bounds__(512) void bq_main_kernel(
    const float* __restrict__ weight,
    const float* __restrict__ w_min,
    const float* __restrict__ w_max,
    float* __restrict__ out,
    float* __restrict__ ent_partial)
{
    // per-thread private 16-bin row, stride 17 dwords (slot 16 = pad + n=15
    // overflow bucket). bank = (17t + n) & 31: bijective per 32-lane half.
    __shared__ float bins[512 * 17];   // 34816 B
    __shared__ float red[16];

    const int bid = blockIdx.x;
    const int br = bid >> 5;
    const int bc = bid & 31;
    const int t = threadIdx.x;      // 0..511
    const int c = t & 127;          // column within block (thread owns it)
    const int rq = t >> 7;          // row quarter: rows [rq*32, rq*32+32)

    float* __restrict__ mybin = &bins[t * 17];
    #pragma unroll
    for (int j = 0; j < 17; ++j) mybin[j] = 0.0f;  // own slots, no barrier needed

    // per-block scale params (reference semantics)
    const float wmn = w_min[bid];
    const float wmx = w_max[bid];
    const float lo = fminf(wmn, wmx - EPS);
    const float hi = fmaxf(wmx, lo + EPS);
    const float scale = hi - lo + EPS;
    const float s15 = 15.0f / scale;
    const float dmm15 = (hi - lo) * (1.0f / 15.0f);
    const float tb0 = -lo * s15;    // th = fmaf(w, s15, tb0) in [0,15]

    const size_t base = (size_t)(br * 128 + rq * 32) * 4096 + (size_t)(bc * 128 + c);
    const float* __restrict__ wp = weight + base;
    float* __restrict__ op = out + base;

    #pragma unroll 4
    for (int i = 0; i < 32; ++i) {
        const float w = wp[(size_t)i * 4096];
        const float th = fmaf(w, s15, tb0);
        const float nf = fminf(fmaxf(floorf(th), 0.0f), 15.0f);
        const int n = (int)nf;
        const float f = th - nf;                              // [0,1)
        // closed-form softmax denominator over 16 geometric terms
        const float qe = fast_exp2(-C2 * f);                  // g^f      (= e_n)
        const float re = fast_exp2(fmaf(C2, f, -C2));         // g^(1-f)  (= e_{n+1})
        const float se = fast_exp2(fmaf(-C2, th, -C2));       // g^(th+1)
        const float te = fast_exp2(fmaf(C2, th, -16.0f * C2));// g^(16-th)
        const float S  = C1 * ((qe + re) - (se + te));
        const float rS = fast_rcp(S);
        // closed-form 15*W (level-weighted sum), verified on-chip in R5
        const float Ax = fmaf(nf, C3, 1.0f);                  // (n+1) - n*g
        const float Bx = fmaf(-nf, C3, C4);                   // (15-n) - (14-n)*g
        const float T2 = fmaf(se, Ax, fmaf(-te, Bx, (re - qe) * GK));
        const float W15 = fmaf(nf, S, fmaf(re - te, C1, T2 * C2P));
        __builtin_nontemporal_store(fmaf(W15 * rS, dmm15, lo), &op[(size_t)i * 4096]);
        // truncated 2-bin histogram update (adjacent slots -> ds_read2/write2)
        mybin[n]     += qe * rS;
        mybin[n + 1] += re * rS;   // n==15 lands in pad slot 16 (dropped, exact)
    }

    __syncthreads();

    // merge 4 row-quarters per column, then entropy
    float s_local = 0.0f, ent = 0.0f;
    float bin[16];
    if (t < 128) {
        #pragma unroll
        for (int j = 0; j < 16; ++j) {
            bin[j] = bins[t * 17 + j] + bins[(128 + t) * 17 + j]
                   + bins[(256 + t) * 17 + j] + bins[(384 + t) * 17 + j];
            s_local += bin[j];
        }
    }

    const float B = block_sum_512(s_local, red, 0);
    const float invB = fast_rcp(B + EPS);

    if (t < 128) {
        #pragma unroll
        for (int j = 0; j < 16; ++j) {
            const float p = bin[j] * invB;
            ent = fmaf(p, __logf(p + EPS), ent);
        }
    }
    const float entB = block_sum_512(ent, red, 1);
    if (t == 0) ent_partial[bid] = -entB;
}

__global__ __launch_bounds__(256) void bq_ent_reduce(
    const float* __restrict__ part, float* __restrict__ out_ent)
{
    __shared__ float red[8];
    const int t = threadIdx.x;  // 256 threads, 1024 partials
    float v = part[t] + part[t + 256] + part[t + 512] + part[t + 768];
    #pragma unroll
    for (int o = 32; o > 0; o >>= 1) v += __shfl_xor(v, o, 64);
    if ((t & 63) == 0) red[t >> 6] = v;
    __syncthreads();
    if (t == 0) out_ent[0] = red[0] + red[1] + red[2] + red[3];
}

extern "C" void kernel_launch(void* const* d_in, const int* in_sizes, int n_in,
                              void* d_out, int out_size, void* d_ws, size_t ws_size,
                              hipStream_t stream) {
    const float* weight = (const float*)d_in[0];
    const float* wmin = (const float*)d_in[1];
    const float* wmax = (const float*)d_in[2];
    float* out = (float*)d_out;
    float* part = (float*)d_ws;  // 1024 floats of scratch

    bq_main_kernel<<<1024, 512, 0, stream>>>(weight, wmin, wmax, out, part);
    bq_ent_reduce<<<1, 256, 0, stream>>>(part, out + (out_size - 1));
}

// Round 7
// 37.244 us; speedup vs baseline: 4.7765x; 1.0248x over previous
//
#include <hip/hip_runtime.h>

#define EPS 1e-6f

// C2 = FIXED_T/(NUM_LEVELS-1) * log2(e) = 100/(15*ln2);  g = 2^-C2 = exp(-100/15)
static constexpr float C2  = 9.617966939259756f;
static constexpr float GK  = 1.2726338013398079e-3f;  // g
static constexpr float C1  = 1.0012742546176476f;     // 1/(1-g)
static constexpr float C2P = 1.0025501329047173f;     // 1/(1-g)^2
static constexpr float C3  = 0.9987273661986602f;     // 1-g
static constexpr float C4  = 14.982183126781242f;     // 15 - 14g

#if __has_builtin(__builtin_amdgcn_exp2f)
__device__ __forceinline__ float fast_exp2(float x) { return __builtin_amdgcn_exp2f(x); }
#else
__device__ __forceinline__ float fast_exp2(float x) { return exp2f(x); }
#endif

#if __has_builtin(__builtin_amdgcn_rcpf)
__device__ __forceinline__ float fast_rcp(float x) { return __builtin_amdgcn_rcpf(x); }
#else
__device__ __forceinline__ float fast_rcp(float x) { return 1.0f / x; }
#endif

// deterministic block-wide sum for 512 threads (8 waves); red has 8 floats/slot
__device__ __forceinline__ float block_sum_512(float v, float* red, int slot) {
    #pragma unroll
    for (int o = 32; o > 0; o >>= 1) v += __shfl_xor(v, o, 64);
    const int t = threadIdx.x;
    __syncthreads();  // protect prior use of red
    if ((t & 63) == 0) red[slot * 8 + (t >> 6)] = v;
    __syncthreads();
    float s = 0.0f;
    #pragma unroll
    for (int wv = 0; wv < 8; ++wv) s += red[slot * 8 + wv];
    return s;
}

__global__ __launch_bounds__(512) void bq_main_kernel(
    const float* __restrict__ weight,
    const float* __restrict__ w_min,
    const float* __restrict__ w_max,
    float* __restrict__ out,
    float* __restrict__ ent_partial)
{
    // one packed bin row per COLUMN (shared by its 4 row-quarter threads via
    // ds_add_u32). slot j holds (sum_v<<16 | sum_u) in 9-bit fixed point.
    // stride 17 dwords decorrelates banks.
    __shared__ unsigned int bins[128 * 17];   // 8704 B
    __shared__ float red[16];

    const int bid = blockIdx.x;
    const int br = bid >> 5;
    const int bc = bid & 31;
    const int t = threadIdx.x;      // 0..511
    const int c = t & 127;          // column within block
    const int rq = t >> 7;          // row quarter: rows [rq*32, rq*32+32)

    #pragma unroll
    for (int i = 0; i < 5; ++i) {
        const int idx = t + i * 512;
        if (idx < 128 * 17) bins[idx] = 0u;
    }

    // per-block scale params (reference semantics)
    const float wmn = w_min[bid];
    const float wmx = w_max[bid];
    const float lo = fminf(wmn, wmx - EPS);
    const float hi = fmaxf(wmx, lo + EPS);
    const float scale = hi - lo + EPS;
    const float s15 = 15.0f / scale;
    const float dmm15 = (hi - lo) * (1.0f / 15.0f);
    const float tb0 = -lo * s15;    // th = fmaf(w, s15, tb0) in [0,15)

    __syncthreads();

    const size_t base = (size_t)(br * 128 + rq * 32) * 4096 + (size_t)(bc * 128 + c);
    const float* __restrict__ wp = weight + base;
    float* __restrict__ op = out + base;
    unsigned int* __restrict__ crow = &bins[c * 17];

    #pragma unroll 8
    for (int i = 0; i < 32; ++i) {
        const float w = wp[(size_t)i * 4096];
        const float th = fmaf(w, s15, tb0);
        const float nf = fminf(fmaxf(floorf(th), 0.0f), 15.0f);
        const int n = (int)nf;
        const float f = th - nf;                              // [0,1)
        // closed-form softmax denominator over 16 geometric terms
        const float qe = fast_exp2(-C2 * f);                  // g^f      (= e_n)
        const float re = fast_exp2(fmaf(C2, f, -C2));         // g^(1-f)  (= e_{n+1})
        const float se = fast_exp2(fmaf(-C2, th, -C2));       // g^(th+1)
        const float te = fast_exp2(fmaf(C2, th, -16.0f * C2));// g^(16-th)
        const float S  = C1 * ((qe + re) - (se + te));
        const float rS = fast_rcp(S);
        // closed-form 15*W (level-weighted sum), on-chip verified (R5/R6)
        const float Ax = fmaf(nf, C3, 1.0f);                  // (n+1) - n*g
        const float Bx = fmaf(-nf, C3, C4);                   // (15-n) - (14-n)*g
        const float T2 = fmaf(se, Ax, fmaf(-te, Bx, (re - qe) * GK));
        const float W15 = fmaf(nf, S, fmaf(re - te, C1, T2 * C2P));
        __builtin_nontemporal_store(fmaf(W15 * rS, dmm15, lo), &op[(size_t)i * 4096]);
        // packed fixed-point 2-bin deposit: u -> bin n (lo16), v -> bin n+1 (hi16)
        const unsigned int ui = (unsigned int)fmaf(qe * rS, 512.0f, 0.5f);
        const unsigned int vi = (unsigned int)fmaf(re * rS, 512.0f, 0.5f);
        atomicAdd(&crow[n], ui | (vi << 16));                 // ds_add_u32
    }

    __syncthreads();

    // epilogue: bin[j] = (lo16(slot j) + hi16(slot j-1)) / 512, then entropy
    float s_local = 0.0f, ent = 0.0f;
    float bin[16];
    if (t < 128) {
        unsigned int prev = 0u;
        #pragma unroll
        for (int j = 0; j < 16; ++j) {
            const unsigned int cur = bins[t * 17 + j];
            bin[j] = (float)((cur & 0xFFFFu) + (prev >> 16)) * (1.0f / 512.0f);
            prev = cur;
            s_local += bin[j];
        }
    }

    const float B = block_sum_512(s_local, red, 0);
    const float invB = fast_rcp(B + EPS);

    if (t < 128) {
        #pragma unroll
        for (int j = 0; j < 16; ++j) {
            const float p = bin[j] * invB;
            ent = fmaf(p, __logf(p + EPS), ent);
        }
    }
    const float entB = block_sum_512(ent, red, 1);
    if (t == 0) ent_partial[bid] = -entB;
}

__global__ __launch_bounds__(256) void bq_ent_reduce(
    const float* __restrict__ part, float* __restrict__ out_ent)
{
    __shared__ float red[8];
    const int t = threadIdx.x;  // 256 threads, 1024 partials
    float v = part[t] + part[t + 256] + part[t + 512] + part[t + 768];
    #pragma unroll
    for (int o = 32; o > 0; o >>= 1) v += __shfl_xor(v, o, 64);
    if ((t & 63) == 0) red[t >> 6] = v;
    __syncthreads();
    if (t == 0) out_ent[0] = red[0] + red[1] + red[2] + red[3];
}

extern "C" void kernel_launch(void* const* d_in, const int* in_sizes, int n_in,
                              void* d_out, int out_size, void* d_ws, size_t ws_size,
                              hipStream_t stream) {
    const float* weight = (const float*)d_in[0];
    const float* wmin = (const float*)d_in[1];
    const float* wmax = (const float*)d_in[2];
    float* out = (float*)d_out;
    float* part = (float*)d_ws;  // 1024 floats of scratch

    bq_main_kernel<<<1024, 512, 0, stream>>>(weight, wmin, wmax, out, part);
    bq_ent_reduce<<<1, 256, 0, stream>>>(part, out + (out_size - 1));
}

// Round 8
// 33.824 us; speedup vs baseline: 5.2595x; 1.1011x over previous
//
#include <hip/hip_runtime.h>

#define EPS 1e-6f

// C2 = FIXED_T/(NUM_LEVELS-1) * log2(e) = 100/(15*ln2);  g = 2^-C2 = exp(-100/15)
static constexpr float C2  = 9.617966939259756f;
static constexpr float GK  = 1.2726338013398079e-3f;  // g
static constexpr float C1  = 1.0012742546176476f;     // 1/(1-g)
static constexpr float C2P = 1.0025501329047173f;     // 1/(1-g)^2
static constexpr float C3  = 0.9987273661986602f;     // 1-g
static constexpr float C4  = 14.982183126781242f;     // 15 - 14g

typedef float floatx4 __attribute__((ext_vector_type(4)));

#if __has_builtin(__builtin_amdgcn_exp2f)
__device__ __forceinline__ float fast_exp2(float x) { return __builtin_amdgcn_exp2f(x); }
#else
__device__ __forceinline__ float fast_exp2(float x) { return exp2f(x); }
#endif

#if __has_builtin(__builtin_amdgcn_rcpf)
__device__ __forceinline__ float fast_rcp(float x) { return __builtin_amdgcn_rcpf(x); }
#else
__device__ __forceinline__ float fast_rcp(float x) { return 1.0f / x; }
#endif

// deterministic block-wide sum for 512 threads (8 waves); red has 8 floats/slot
__device__ __forceinline__ float block_sum_512(float v, float* red, int slot) {
    #pragma unroll
    for (int o = 32; o > 0; o >>= 1) v += __shfl_xor(v, o, 64);
    const int t = threadIdx.x;
    __syncthreads();  // protect prior use of red
    if ((t & 63) == 0) red[slot * 8 + (t >> 6)] = v;
    __syncthreads();
    float s = 0.0f;
    #pragma unroll
    for (int wv = 0; wv < 8; ++wv) s += red[slot * 8 + wv];
    return s;
}

__global__ __launch_bounds__(512) void bq_main_kernel(
    const float* __restrict__ weight,
    const float* __restrict__ w_min,
    const float* __restrict__ w_max,
    float* __restrict__ out,
    float* __restrict__ ent_partial)
{
    // bins[n*128 + slot], slot(col) = 32*(col&3) + (col>>2).
    // bank = slot&31 = cq -> distinct per 32-lane half, 2-way across halves (free).
    // value = (sum_v << 16) | sum_u in x511 fixed point (max 128*511 = 65408).
    __shared__ unsigned int bins[16 * 128];   // 8 KB
    __shared__ float red[16];

    const int bid = blockIdx.x;
    const int br = bid >> 5;
    const int bc = bid & 31;
    const int t = threadIdx.x;      // 0..511
    const int cq = t & 31;          // column quad (cols 4cq..4cq+3)
    const int rg = t >> 5;          // row group (16 groups x 8 rows)
    const int kx = (rg & 1) << 1;   // stagger: wave halves process k in different order

    #pragma unroll
    for (int i = 0; i < 4; ++i) bins[t + i * 512] = 0u;

    // per-block scale params (reference semantics)
    const float wmn = w_min[bid];
    const float wmx = w_max[bid];
    const float lo = fminf(wmn, wmx - EPS);
    const float hi = fmaxf(wmx, lo + EPS);
    const float scale = hi - lo + EPS;
    const float s15 = 15.0f / scale;
    const float dmm15 = (hi - lo) * (1.0f / 15.0f);
    const float tb0 = -lo * s15;    // th = fmaf(w, s15, tb0) in [0,15]

    __syncthreads();

    const size_t base = (size_t)(br * 128 + rg * 8) * 4096 + (size_t)(bc * 128 + cq * 4);
    const floatx4* __restrict__ wp = (const floatx4*)(weight + base);
    floatx4* __restrict__ op = (floatx4*)(out + base);

    #pragma unroll 4
    for (int i = 0; i < 8; ++i) {
        const floatx4 w4 = wp[(size_t)i * 1024];
        floatx4 o4;
        #pragma unroll
        for (int kk = 0; kk < 4; ++kk) {
            const int k = kk ^ kx;   // halves staggered -> no same-address atomics
            const float th = fmaf(w4[k], s15, tb0);
            const float nf = fminf(fmaxf(floorf(th), 0.0f), 15.0f);
            const int n = (int)nf;
            const float f = th - nf;                              // ~[0,1)
            // closed-form softmax denominator over 16 geometric terms
            const float qe = fast_exp2(-C2 * f);                  // g^f      (= e_n)
            const float re = fast_exp2(fmaf(C2, f, -C2));         // g^(1-f)  (= e_{n+1})
            const float se = fast_exp2(fmaf(-C2, th, -C2));       // g^(th+1)
            const float te = fast_exp2(fmaf(C2, th, -16.0f * C2));// g^(16-th)
            const float S  = C1 * ((qe + re) - (se + te));
            const float rS = fast_rcp(S);
            // closed-form 15*W (level-weighted sum), on-chip verified (R5-R7)
            const float Ax = fmaf(nf, C3, 1.0f);                  // (n+1) - n*g
            const float Bx = fmaf(-nf, C3, C4);                   // (15-n) - (14-n)*g
            const float T2 = fmaf(se, Ax, fmaf(-te, Bx, (re - qe) * GK));
            const float W15 = fmaf(nf, S, fmaf(re - te, C1, T2 * C2P));
            o4[k] = fmaf(W15 * rS, dmm15, lo);
            // packed fixed-point 2-bin deposit: u -> bin n (lo16), v -> bin n+1 (hi16)
            const unsigned int ui = (unsigned int)fmaf(qe * rS, 511.0f, 0.5f);
            const unsigned int vi = (unsigned int)fmaf(re * rS, 511.0f, 0.5f);
            atomicAdd(&bins[n * 128 + (k << 5) + cq], ui | (vi << 16));  // ds_add_u32
        }
        __builtin_nontemporal_store(o4, &op[(size_t)i * 1024]);
    }

    __syncthreads();

    // epilogue: bin[j] = (lo16(slot j) + hi16(slot j-1))/511 per column-slot
    float s_local = 0.0f, ent = 0.0f;
    float bin[16];
    if (t < 128) {
        unsigned int prev = 0u;
        #pragma unroll
        for (int j = 0; j < 16; ++j) {
            const unsigned int cur = bins[j * 128 + t];
            bin[j] = (float)((cur & 0xFFFFu) + (prev >> 16)) * (1.0f / 511.0f);
            prev = cur;
            s_local += bin[j];
        }
    }

    const float B = block_sum_512(s_local, red, 0);
    const float invB = fast_rcp(B + EPS);

    if (t < 128) {
        #pragma unroll
        for (int j = 0; j < 16; ++j) {
            const float p = bin[j] * invB;
            ent = fmaf(p, __logf(p + EPS), ent);
        }
    }
    const float entB = block_sum_512(ent, red, 1);
    if (t == 0) ent_partial[bid] = -entB;
}

__global__ __launch_bounds__(256) void bq_ent_reduce(
    const float* __restrict__ part, float* __restrict__ out_ent)
{
    __shared__ float red[8];
    const int t = threadIdx.x;  // 256 threads, 1024 partials
    float v = part[t] + part[t + 256] + part[t + 512] + part[t + 768];
    #pragma unroll
    for (int o = 32; o > 0; o >>= 1) v += __shfl_xor(v, o, 64);
    if ((t & 63) == 0) red[t >> 6] = v;
    __syncthreads();
    if (t == 0) out_ent[0] = red[0] + red[1] + red[2] + red[3];
}

extern "C" void kernel_launch(void* const* d_in, const int* in_sizes, int n_in,
                              void* d_out, int out_size, void* d_ws, size_t ws_size,
                              hipStream_t stream) {
    const float* weight = (const float*)d_in[0];
    const float* wmin = (const float*)d_in[1];
    const float* wmax = (const float*)d_in[2];
    float* out = (float*)d_out;
    float* part = (float*)d_ws;  // 1024 floats of scratch

    bq_main_kernel<<<1024, 512, 0, stream>>>(weight, wmin, wmax, out, part);
    bq_ent_reduce<<<1, 256, 0, stream>>>(part, out + (out_size - 1));
}

// Round 9
// 31.800 us; speedup vs baseline: 5.5942x; 1.0636x over previous
//
#include <hip/hip_runtime.h>

#define EPS 1e-6f

// C2 = FIXED_T/(NUM_LEVELS-1) * log2(e) = 100/(15*ln2);  g = 2^-C2 = exp(-100/15)
static constexpr float C2  = 9.617966939259756f;
static constexpr float GC  = 1.2742546176474651e-3f;  // g/(1-g)
static constexpr float C3  = 0.9987273661986602f;     // 1-g
static constexpr float D1  = 511.0f * C3;             // deposit scale

typedef float floatx4 __attribute__((ext_vector_type(4)));

#if __has_builtin(__builtin_amdgcn_exp2f)
__device__ __forceinline__ float fast_exp2(float x) { return __builtin_amdgcn_exp2f(x); }
#else
__device__ __forceinline__ float fast_exp2(float x) { return exp2f(x); }
#endif

#if __has_builtin(__builtin_amdgcn_rcpf)
__device__ __forceinline__ float fast_rcp(float x) { return __builtin_amdgcn_rcpf(x); }
#else
__device__ __forceinline__ float fast_rcp(float x) { return 1.0f / x; }
#endif

// deterministic block-wide sum for 512 threads (8 waves); red has 8 floats/slot
__device__ __forceinline__ float block_sum_512(float v, float* red, int slot) {
    #pragma unroll
    for (int o = 32; o > 0; o >>= 1) v += __shfl_xor(v, o, 64);
    const int t = threadIdx.x;
    __syncthreads();  // protect prior use of red
    if ((t & 63) == 0) red[slot * 8 + (t >> 6)] = v;
    __syncthreads();
    float s = 0.0f;
    #pragma unroll
    for (int wv = 0; wv < 8; ++wv) s += red[slot * 8 + wv];
    return s;
}

__global__ __launch_bounds__(512) void bq_main_kernel(
    const float* __restrict__ weight,
    const float* __restrict__ w_min,
    const float* __restrict__ w_max,
    float* __restrict__ out,
    float* __restrict__ ent_partial)
{
    // bins[n*128 + slot], slot(col) = 32*(col&3) + (col>>2).
    // bank = slot&31 = cq -> distinct per 32-lane half, 2-way across halves (free).
    // value = (sum_v << 16) | sum_u in x511*(1-g) fixed point (max 128*510 = 65280).
    __shared__ unsigned int bins[16 * 128];   // 8 KB
    __shared__ float red[16];

    const int bid = blockIdx.x;
    const int br = bid >> 5;
    const int bc = bid & 31;
    const int t = threadIdx.x;      // 0..511
    const int cq = t & 31;          // column quad (cols 4cq..4cq+3)
    const int rg = t >> 5;          // row group (16 groups x 8 rows)
    const int kx = rg & 1;          // stagger flag: wave halves use different k order

    #pragma unroll
    for (int i = 0; i < 4; ++i) bins[t + i * 512] = 0u;

    // per-block scale params (reference semantics)
    const float wmn = w_min[bid];
    const float wmx = w_max[bid];
    const float lo = fminf(wmn, wmx - EPS);
    const float hi = fmaxf(wmx, lo + EPS);
    const float scale = hi - lo + EPS;
    const float s15 = 15.0f / scale;
    const float dmm15 = (hi - lo) * (1.0f / 15.0f);
    const float tb0 = -lo * s15;    // th = fmaf(w, s15, tb0) in [0,15]
    // o = nf*A1 + phi*A2 + A3  (exact 2-bin closed form; gc-term cancels
    // truncation asymmetry so interior f=0 reproduces the full ladder)
    const float A1 = dmm15;
    const float A2 = dmm15 * (1.0f + 2.0f * GC);
    const float A3 = lo - GC * dmm15;

    __syncthreads();

    const size_t base = (size_t)(br * 128 + rg * 8) * 4096 + (size_t)(bc * 128 + cq * 4);
    const floatx4* __restrict__ wp = (const floatx4*)(weight + base);
    floatx4* __restrict__ op = (floatx4*)(out + base);

    // K is a literal -> static vector extracts/inserts, compile-time lds offset
    #define PROC(K) do {                                                        \
        const float th = fmaf(w4[K], s15, tb0);                                 \
        const float nf = fminf(fmaxf(floorf(th), 0.0f), 15.0f);                 \
        const int   n  = (int)nf;                                               \
        const float f  = th - nf;                                               \
        const float z  = fast_exp2(fmaf(-2.0f * C2, f, C2));  /* g^(2f-1) */    \
        const float phi = fast_rcp(1.0f + z);                 /* re/(qe+re) */  \
        o4[K] = fmaf(nf, A1, fmaf(phi, A2, A3));                                \
        const unsigned int ui = (unsigned int)fmaf(-phi, D1, D1 + 0.5f);        \
        const unsigned int vi = (unsigned int)fmaf(phi, D1, 0.5f);              \
        atomicAdd(&bins[n * 128 + (K << 5) + cq], ui | (vi << 16));             \
    } while (0)

    #pragma unroll 4
    for (int i = 0; i < 8; ++i) {
        const floatx4 w4 = wp[(size_t)i * 1024];
        floatx4 o4;
        if (kx == 0) { PROC(0); PROC(1); PROC(2); PROC(3); }
        else         { PROC(2); PROC(3); PROC(0); PROC(1); }
        __builtin_nontemporal_store(o4, &op[(size_t)i * 1024]);
    }
    #undef PROC

    __syncthreads();

    // epilogue: bin[j] = lo16(slot j) + hi16(slot j-1) per column-slot
    // (constant scale factors cancel in the normalization)
    float s_local = 0.0f, ent = 0.0f;
    float bin[16];
    if (t < 128) {
        unsigned int prev = 0u;
        #pragma unroll
        for (int j = 0; j < 16; ++j) {
            const unsigned int cur = bins[j * 128 + t];
            bin[j] = (float)((cur & 0xFFFFu) + (prev >> 16));
            prev = cur;
            s_local += bin[j];
        }
    }

    const float B = block_sum_512(s_local, red, 0);
    const float invB = fast_rcp(B + EPS);

    if (t < 128) {
        #pragma unroll
        for (int j = 0; j < 16; ++j) {
            const float p = bin[j] * invB;
            ent = fmaf(p, __logf(p + EPS), ent);
        }
    }
    const float entB = block_sum_512(ent, red, 1);
    if (t == 0) ent_partial[bid] = -entB;
}

__global__ __launch_bounds__(256) void bq_ent_reduce(
    const float* __restrict__ part, float* __restrict__ out_ent)
{
    __shared__ float red[8];
    const int t = threadIdx.x;  // 256 threads, 1024 partials
    float v = part[t] + part[t + 256] + part[t + 512] + part[t + 768];
    #pragma unroll
    for (int o = 32; o > 0; o >>= 1) v += __shfl_xor(v, o, 64);
    if ((t & 63) == 0) red[t >> 6] = v;
    __syncthreads();
    if (t == 0) out_ent[0] = red[0] + red[1] + red[2] + red[3];
}

extern "C" void kernel_launch(void* const* d_in, const int* in_sizes, int n_in,
                              void* d_out, int out_size, void* d_ws, size_t ws_size,
                              hipStream_t stream) {
    const float* weight = (const float*)d_in[0];
    const float* wmin = (const float*)d_in[1];
    const float* wmax = (const float*)d_in[2];
    float* out = (float*)d_out;
    float* part = (float*)d_ws;  // 1024 floats of scratch

    bq_main_kernel<<<1024, 512, 0, stream>>>(weight, wmin, wmax, out, part);
    bq_ent_reduce<<<1, 256, 0, stream>>>(part, out + (out_size - 1));
}

// Round 10
// 31.163 us; speedup vs baseline: 5.7085x; 1.0204x over previous
//
#include <hip/hip_runtime.h>

#define EPS 1e-6f

// C2 = FIXED_T/(NUM_LEVELS-1) * log2(e) = 100/(15*ln2);  g = 2^-C2 = exp(-100/15)
static constexpr float C2  = 9.617966939259756f;
static constexpr float GC  = 1.2742546176474651e-3f;  // g/(1-g)
static constexpr float C3  = 0.9987273661986602f;     // 1-g
static constexpr float D1  = 511.0f * C3;             // deposit scale

typedef float floatx4 __attribute__((ext_vector_type(4)));

#if __has_builtin(__builtin_amdgcn_exp2f)
__device__ __forceinline__ float fast_exp2(float x) { return __builtin_amdgcn_exp2f(x); }
#else
__device__ __forceinline__ float fast_exp2(float x) { return exp2f(x); }
#endif

#if __has_builtin(__builtin_amdgcn_rcpf)
__device__ __forceinline__ float fast_rcp(float x) { return __builtin_amdgcn_rcpf(x); }
#else
__device__ __forceinline__ float fast_rcp(float x) { return 1.0f / x; }
#endif

// deterministic block-wide sum for 512 threads (8 waves); red has 8 floats/slot
__device__ __forceinline__ float block_sum_512(float v, float* red, int slot) {
    #pragma unroll
    for (int o = 32; o > 0; o >>= 1) v += __shfl_xor(v, o, 64);
    const int t = threadIdx.x;
    __syncthreads();  // protect prior use of red
    if ((t & 63) == 0) red[slot * 8 + (t >> 6)] = v;
    __syncthreads();
    float s = 0.0f;
    #pragma unroll
    for (int wv = 0; wv < 8; ++wv) s += red[slot * 8 + wv];
    return s;
}

__global__ __launch_bounds__(512, 8) void bq_main_kernel(
    const float* __restrict__ weight,
    const float* __restrict__ w_min,
    const float* __restrict__ w_max,
    float* __restrict__ out,
    float* __restrict__ ent_partial)
{
    // bins[n*128 + slot], slot(col) = 32*(col&3) + (col>>2).
    // bank = slot&31 = cq -> distinct per 32-lane half, 2-way across halves (free).
    // value = (sum_v << 16) | sum_u in x511*(1-g) fixed point (max 128*510 = 65280).
    __shared__ unsigned int bins[16 * 128];   // 8 KB
    __shared__ float red[16];

    const int bid = blockIdx.x;
    const int br = bid >> 5;
    const int bc = bid & 31;
    const int t = threadIdx.x;      // 0..511
    const int cq = t & 31;          // column quad (cols 4cq..4cq+3)
    const int rg = t >> 5;          // row group (16 groups x 8 rows)
    const int kx = rg & 1;          // stagger flag: wave halves use different k order

    #pragma unroll
    for (int i = 0; i < 4; ++i) bins[t + i * 512] = 0u;

    // per-block scale params (reference semantics)
    const float wmn = w_min[bid];
    const float wmx = w_max[bid];
    const float lo = fminf(wmn, wmx - EPS);
    const float hi = fmaxf(wmx, lo + EPS);
    const float scale = hi - lo + EPS;
    const float s15 = 15.0f / scale;
    const float dmm15 = (hi - lo) * (1.0f / 15.0f);
    const float tb0 = -lo * s15;    // th = fmaf(w, s15, tb0) in [0,15]
    // o = nf*A1 + phi*A2 + A3  (exact 2-bin closed form; gc-term cancels
    // truncation asymmetry so interior f=0 reproduces the full ladder)
    const float A1 = dmm15;
    const float A2 = dmm15 * (1.0f + 2.0f * GC);
    const float A3 = lo - GC * dmm15;

    __syncthreads();

    const size_t base = (size_t)(br * 128 + rg * 8) * 4096 + (size_t)(bc * 128 + cq * 4);
    const floatx4* __restrict__ wp = (const floatx4*)(weight + base);
    floatx4* __restrict__ op = (floatx4*)(out + base);

    // ---- issue ALL loads up front: one HBM latency exposure per thread ----
    floatx4 w[8];
    #pragma unroll
    for (int i = 0; i < 8; ++i) w[i] = wp[(size_t)i * 1024];

    // K is a literal -> static vector extracts/inserts, compile-time lds offset
    #define PROC(I, K) do {                                                     \
        const float th = fmaf(w[I][K], s15, tb0);                               \
        const float nf = fminf(fmaxf(floorf(th), 0.0f), 15.0f);                 \
        const int   n  = (int)nf;                                               \
        const float f  = th - nf;                                               \
        const float z  = fast_exp2(fmaf(-2.0f * C2, f, C2));  /* g^(2f-1) */    \
        const float phi = fast_rcp(1.0f + z);                 /* re/(qe+re) */  \
        o4[K] = fmaf(nf, A1, fmaf(phi, A2, A3));                                \
        const unsigned int ui = (unsigned int)fmaf(-phi, D1, D1 + 0.5f);        \
        const unsigned int vi = (unsigned int)fmaf(phi, D1, 0.5f);              \
        atomicAdd(&bins[n * 128 + (K << 5) + cq], ui | (vi << 16));             \
    } while (0)

    #pragma unroll
    for (int i = 0; i < 8; ++i) {
        floatx4 o4;
        if (kx == 0) { PROC(i, 0); PROC(i, 1); PROC(i, 2); PROC(i, 3); }
        else         { PROC(i, 2); PROC(i, 3); PROC(i, 0); PROC(i, 1); }
        __builtin_nontemporal_store(o4, &op[(size_t)i * 1024]);
    }
    #undef PROC

    __syncthreads();

    // epilogue: bin[j] = lo16(slot j) + hi16(slot j-1) per column-slot
    // (constant scale factors cancel in the normalization)
    float s_local = 0.0f, ent = 0.0f;
    float bin[16];
    if (t < 128) {
        unsigned int prev = 0u;
        #pragma unroll
        for (int j = 0; j < 16; ++j) {
            const unsigned int cur = bins[j * 128 + t];
            bin[j] = (float)((cur & 0xFFFFu) + (prev >> 16));
            prev = cur;
            s_local += bin[j];
        }
    }

    const float B = block_sum_512(s_local, red, 0);
    const float invB = fast_rcp(B + EPS);

    if (t < 128) {
        #pragma unroll
        for (int j = 0; j < 16; ++j) {
            const float p = bin[j] * invB;
            ent = fmaf(p, __logf(p + EPS), ent);
        }
    }
    const float entB = block_sum_512(ent, red, 1);
    if (t == 0) ent_partial[bid] = -entB;
}

__global__ __launch_bounds__(64) void bq_ent_reduce(
    const float* __restrict__ part, float* __restrict__ out_ent)
{
    const int t = threadIdx.x;  // 64 threads, 1024 partials
    float v = 0.0f;
    #pragma unroll
    for (int i = 0; i < 16; ++i) v += part[t + i * 64];
    #pragma unroll
    for (int o = 32; o > 0; o >>= 1) v += __shfl_xor(v, o, 64);
    if (t == 0) out_ent[0] = v;
}

extern "C" void kernel_launch(void* const* d_in, const int* in_sizes, int n_in,
                              void* d_out, int out_size, void* d_ws, size_t ws_size,
                              hipStream_t stream) {
    const float* weight = (const float*)d_in[0];
    const float* wmin = (const float*)d_in[1];
    const float* wmax = (const float*)d_in[2];
    float* out = (float*)d_out;
    float* part = (float*)d_ws;  // 1024 floats of scratch

    bq_main_kernel<<<1024, 512, 0, stream>>>(weight, wmin, wmax, out, part);
    bq_ent_reduce<<<1, 64, 0, stream>>>(part, out + (out_size - 1));
}

// Round 11
// 30.594 us; speedup vs baseline: 5.8148x; 1.0186x over previous
//
#include <hip/hip_runtime.h>

#define EPS 1e-6f

// C2 = FIXED_T/(NUM_LEVELS-1) * log2(e) = 100/(15*ln2);  g = 2^-C2 = exp(-100/15)
static constexpr float C2  = 9.617966939259756f;
static constexpr float GC  = 1.2742546176474651e-3f;  // g/(1-g)
static constexpr float C3  = 0.9987273661986602f;     // 1-g
static constexpr float D1  = 511.0f * C3;             // deposit scale (max 510)

typedef float floatx4 __attribute__((ext_vector_type(4)));

#if __has_builtin(__builtin_amdgcn_exp2f)
__device__ __forceinline__ float fast_exp2(float x) { return __builtin_amdgcn_exp2f(x); }
#else
__device__ __forceinline__ float fast_exp2(float x) { return exp2f(x); }
#endif

#if __has_builtin(__builtin_amdgcn_rcpf)
__device__ __forceinline__ float fast_rcp(float x) { return __builtin_amdgcn_rcpf(x); }
#else
__device__ __forceinline__ float fast_rcp(float x) { return 1.0f / x; }
#endif

// deterministic block-wide sum for 512 threads (8 waves); red has 8 floats/slot
__device__ __forceinline__ float block_sum_512(float v, float* red, int slot) {
    #pragma unroll
    for (int o = 32; o > 0; o >>= 1) v += __shfl_xor(v, o, 64);
    const int t = threadIdx.x;
    __syncthreads();  // protect prior use of red
    if ((t & 63) == 0) red[slot * 8 + (t >> 6)] = v;
    __syncthreads();
    float s = 0.0f;
    #pragma unroll
    for (int wv = 0; wv < 8; ++wv) s += red[slot * 8 + wv];
    return s;
}

__global__ __launch_bounds__(512, 8) void bq_main_kernel(
    const float* __restrict__ weight,
    const float* __restrict__ w_min,
    const float* __restrict__ w_max,
    float* __restrict__ out,
    float* __restrict__ ent_partial)
{
    // bins[n*128 + slot], slot(col) = 32*(col&3) + (col>>2).
    // bank = slot&31 = cq -> distinct per 32-lane half; lanes L/L+32 share an
    // address but a wave64 LDS op is >=2 cyc anyway, so the 2-way atomic is free.
    // value = (sum_v << 16) | sum_u, x511*(1-g) fixed point (max 128*510 = 65280).
    __shared__ unsigned int bins[16 * 128];   // 8 KB
    __shared__ float red[16];

    const int bid = blockIdx.x;
    const int br = bid >> 5;
    const int bc = bid & 31;
    const int t = threadIdx.x;      // 0..511
    const int cq = t & 31;          // column quad (cols 4cq..4cq+3)
    const int rg = t >> 5;          // row group (16 groups x 8 rows)

    #pragma unroll
    for (int i = 0; i < 4; ++i) bins[t + i * 512] = 0u;

    // per-block scale params (reference semantics)
    const float wmn = w_min[bid];
    const float wmx = w_max[bid];
    const float lo = fminf(wmn, wmx - EPS);
    const float hi = fmaxf(wmx, lo + EPS);
    const float scale = hi - lo + EPS;
    const float s15 = 15.0f / scale;
    const float dmm15 = (hi - lo) * (1.0f / 15.0f);
    const float tb0 = -lo * s15;    // th = fmaf(w, s15, tb0) in [0,15]
    // o = nf*A1 + phi*A2 + A3  (exact 2-bin closed form; gc-term cancels
    // truncation asymmetry so interior f=0 reproduces the full ladder)
    const float A1 = dmm15;
    const float A2 = dmm15 * (1.0f + 2.0f * GC);
    const float A3 = lo - GC * dmm15;

    __syncthreads();

    const size_t base = (size_t)(br * 128 + rg * 8) * 4096 + (size_t)(bc * 128 + cq * 4);
    const floatx4* __restrict__ wp = (const floatx4*)(weight + base);
    floatx4* __restrict__ op = (floatx4*)(out + base);

    // K literal -> static extracts, compile-time LDS sub-offsets. NO divergence:
    // all 64 lanes of a wave take the same path (the R8-R10 kx-stagger was an
    // intra-wave divergent branch that doubled the whole hot loop).
    #define PROC(K) do {                                                        \
        const float th = fmaf(w4[K], s15, tb0);                                 \
        const float nf = fminf(fmaxf(floorf(th), 0.0f), 15.0f);                 \
        const int   n  = (int)nf;                                               \
        const float f  = th - nf;                                               \
        const float z  = fast_exp2(fmaf(-2.0f * C2, f, C2));  /* g^(2f-1) */    \
        const float phi = fast_rcp(1.0f + z);                 /* re/(qe+re) */  \
        o4[K] = fmaf(nf, A1, fmaf(phi, A2, A3));                                \
        const unsigned int vi = (unsigned int)fmaf(phi, D1, 0.5f);              \
        atomicAdd(&bins[n * 128 + (K << 5) + cq], vi * 65535u + 510u);          \
    } while (0)

    #pragma unroll
    for (int i = 0; i < 8; ++i) {
        const floatx4 w4 = wp[(size_t)i * 1024];
        floatx4 o4;
        PROC(0); PROC(1); PROC(2); PROC(3);
        __builtin_nontemporal_store(o4, &op[(size_t)i * 1024]);
    }
    #undef PROC

    __syncthreads();

    // epilogue: bin[j] = lo16(slot j) + hi16(slot j-1) per column-slot
    // (constant scale factors cancel in the normalization)
    float s_local = 0.0f, ent = 0.0f;
    float bin[16];
    if (t < 128) {
        unsigned int prev = 0u;
        #pragma unroll
        for (int j = 0; j < 16; ++j) {
            const unsigned int cur = bins[j * 128 + t];
            bin[j] = (float)((cur & 0xFFFFu) + (prev >> 16));
            prev = cur;
            s_local += bin[j];
        }
    }

    const float B = block_sum_512(s_local, red, 0);
    const float invB = fast_rcp(B + EPS);

    if (t < 128) {
        #pragma unroll
        for (int j = 0; j < 16; ++j) {
            const float p = bin[j] * invB;
            ent = fmaf(p, __logf(p + EPS), ent);
        }
    }
    const float entB = block_sum_512(ent, red, 1);
    if (t == 0) ent_partial[bid] = -entB;
}

__global__ __launch_bounds__(64) void bq_ent_reduce(
    const float* __restrict__ part, float* __restrict__ out_ent)
{
    const int t = threadIdx.x;  // 64 threads, 1024 partials
    float v = 0.0f;
    #pragma unroll
    for (int i = 0; i < 16; ++i) v += part[t + i * 64];
    #pragma unroll
    for (int o = 32; o > 0; o >>= 1) v += __shfl_xor(v, o, 64);
    if (t == 0) out_ent[0] = v;
}

extern "C" void kernel_launch(void* const* d_in, const int* in_sizes, int n_in,
                              void* d_out, int out_size, void* d_ws, size_t ws_size,
                              hipStream_t stream) {
    const float* weight = (const float*)d_in[0];
    const float* wmin = (const float*)d_in[1];
    const float* wmax = (const float*)d_in[2];
    float* out = (float*)d_out;
    float* part = (float*)d_ws;  // 1024 floats of scratch

    bq_main_kernel<<<1024, 512, 0, stream>>>(weight, wmin, wmax, out, part);
    bq_ent_reduce<<<1, 64, 0, stream>>>(part, out + (out_size - 1));
}